// Round 16
// baseline (243.800 us; speedup 1.0000x reference)
//
#include <hip/hip_runtime.h>

#define N_NODES 50000
#define N_EDGES 800000
#define NFEAT   128
#define HID     64
#define EPS_BN  1e-5f
#define NCHUNK  2
#define CHN     (N_NODES / NCHUNK)          // 25000: src chunk split
#define SENT    50000                       // sentinel src (zeroed plane row)

// ---- binned edge sort params
#define NPB     256                         // dst nodes per coarse bin (t>>8)
#define NCBIN   196                         // ceil(50000/256)
#define BPB     (NPB * NCHUNK)              // buckets per bin = 512
#define EPBLK   2048
#define NB1     ((N_EDGES + EPBLK - 1) / EPBLK)   // 391
#define MAXPAD  (3 * BPB + 4)               // per-bin col slack

// ---- degree sort params
#define NBINS   64
#define NBLKN   ((N_NODES + 255) / 256)     // 196
#define NPAIR   (N_NODES / 2)               // 25000 complementary pairs

typedef unsigned int   u32x4 __attribute__((ext_vector_type(4)));
typedef unsigned int   u32x2 __attribute__((ext_vector_type(2)));
typedef unsigned short u16x4 __attribute__((ext_vector_type(4)));

// bf16 helpers
__device__ __forceinline__ float u2f_lo(unsigned int u) {
    union { unsigned int i; float f; } c; c.i = u << 16; return c.f;
}
__device__ __forceinline__ float u2f_hi(unsigned int u) {
    union { unsigned int i; float f; } c; c.i = u & 0xffff0000u; return c.f;
}
__device__ __forceinline__ float b2f(unsigned short u) {
    union { unsigned int i; float f; } c; c.i = ((unsigned int)u) << 16; return c.f;
}
__device__ __forceinline__ unsigned int f2b2(float lo, float hi) {
    union { float f; unsigned int i; } a, b;
    a.f = lo; b.f = hi;
    unsigned int x = (a.i + 0x7fffu + ((a.i >> 16) & 1u)) >> 16;
    unsigned int y = (b.i + 0x7fffu + ((b.i >> 16) & 1u)) & 0xffff0000u;
    return x | y;
}

// ---------------------------------------------------------------------------
__global__ void k_zero(float* __restrict__ st0, float* __restrict__ st1,
                       unsigned short* __restrict__ ts0,
                       unsigned short* __restrict__ ts1,
                       unsigned short* __restrict__ sent) {
    int i = threadIdx.x;
    if (i < 2 * HID) { st0[i] = 0.f; st1[i] = 0.f; }
    if (i < 16) ((unsigned int*)(ts0 + (size_t)SENT * 32))[i] = 0u;  // zero rows
    if (i < 16) ((unsigned int*)(ts1 + (size_t)SENT * 32))[i] = 0u;
    if (i < 4) sent[i] = SENT;
}

// ---------------------------------------------------------------------------
// binned edge sort
// ---------------------------------------------------------------------------
__global__ __launch_bounds__(256) void k_p1(const int* __restrict__ ei,
                                            unsigned int* __restrict__ packed,
                                            unsigned short* __restrict__ lrankE,
                                            int* __restrict__ bhE) {
    __shared__ int h[NCBIN];
    const int tid = threadIdx.x;
    for (int i = tid; i < NCBIN; i += 256) h[i] = 0;
    __syncthreads();
    const int base = blockIdx.x * EPBLK;
#pragma unroll
    for (int it = 0; it < EPBLK / 256; ++it) {
        int e = base + it * 256 + tid;
        if (e < N_EDGES) {
            unsigned s = (unsigned)ei[e];
            unsigned t = (unsigned)ei[N_EDGES + e];
            packed[e] = (t << 16) | s;
            lrankE[e] = (unsigned short)atomicAdd(&h[t >> 8], 1);
        }
    }
    __syncthreads();
    for (int i = tid; i < NCBIN; i += 256) bhE[i * NB1 + blockIdx.x] = h[i];
}

__global__ __launch_bounds__(512) void k_p1scan(int* __restrict__ bhE,
                                                int* __restrict__ bintotE) {
    const int b = blockIdx.x, tid = threadIdx.x;
    int v = (tid < NB1) ? bhE[b * NB1 + tid] : 0;
    __shared__ int sm[512];
    sm[tid] = v;
    __syncthreads();
    for (int off = 1; off < 512; off <<= 1) {
        int t = (tid >= off) ? sm[tid - off] : 0;
        __syncthreads();
        sm[tid] += t;
        __syncthreads();
    }
    if (tid < NB1) bhE[b * NB1 + tid] = sm[tid] - v;
    if (tid == 511) bintotE[b] = sm[511];
}

__global__ void k_binbase(const int* __restrict__ bintotE, int* __restrict__ binbase) {
    const int tid = threadIdx.x;
    int v = (tid < NCBIN) ? bintotE[tid] : 0;
    __shared__ int sm[256];
    sm[tid] = v;
    __syncthreads();
    for (int off = 1; off < 256; off <<= 1) {
        int t = (tid >= off) ? sm[tid - off] : 0;
        __syncthreads();
        sm[tid] += t;
        __syncthreads();
    }
    if (tid < NCBIN) binbase[tid] = sm[tid] - v;
    if (tid == NCBIN - 1) binbase[NCBIN] = sm[tid];
}

__global__ __launch_bounds__(256) void k_p3(const unsigned int* __restrict__ packed,
                                            const unsigned short* __restrict__ lrankE,
                                            const int* __restrict__ bhE,
                                            const int* __restrict__ binbase,
                                            unsigned int* __restrict__ binned) {
    const int base = blockIdx.x * EPBLK;
#pragma unroll
    for (int it = 0; it < EPBLK / 256; ++it) {
        int e = base + it * 256 + threadIdx.x;
        if (e < N_EDGES) {
            unsigned p = packed[e];
            int bin = (int)(p >> 24);
            int pos = binbase[bin] + bhE[bin * NB1 + blockIdx.x] + lrankE[e];
            binned[pos] = p;
        }
    }
}

__global__ __launch_bounds__(256) void k_p4(const unsigned int* __restrict__ binned,
                                            const int* __restrict__ binbase,
                                            unsigned short* __restrict__ col,
                                            int2* __restrict__ nspan,
                                            float* __restrict__ dinv) {
    __shared__ int cnt[BPB];
    __shared__ int lrp[BPB];
    __shared__ int fillc[BPB];
    __shared__ int scanTmp[256];
    const int bin = blockIdx.x, tid = threadIdx.x;
    const int e0 = binbase[bin], e1 = binbase[bin + 1];
    const int t0 = bin * NPB;
    for (int i = tid; i < BPB; i += 256) { cnt[i] = 0; fillc[i] = 0; }
    __syncthreads();
    for (int i = e0 + tid; i < e1; i += 256) {
        unsigned p = binned[i];
        int t = (int)(p >> 16), s = (int)(p & 0xffffu);
        int lb = ((t - t0) << 1) | (s >= CHN);
        atomicAdd(&cnt[lb], 1);
    }
    __syncthreads();
    const int p0 = (cnt[2 * tid] + 3) & ~3;
    const int p1 = (cnt[2 * tid + 1] + 3) & ~3;
    const int mysum = p0 + p1;
    scanTmp[tid] = mysum;
    __syncthreads();
    for (int off = 1; off < 256; off <<= 1) {
        int t = (tid >= off) ? scanTmp[tid - off] : 0;
        __syncthreads();
        scanTmp[tid] += t;
        __syncthreads();
    }
    const int pre = scanTmp[tid] - mysum;
    lrp[2 * tid]     = pre;
    lrp[2 * tid + 1] = pre + p0;
    const int colbase = ((e0 + 3) & ~3) + bin * MAXPAD;
    {
        const int node = t0 + tid;
        if (node < N_NODES) {
            int st = colbase + pre;
            nspan[node] = make_int2(st, st + p0 + p1);
            dinv[node] = rsqrtf((float)(cnt[2 * tid] + cnt[2 * tid + 1] + 1));
        }
    }
    __syncthreads();
    for (int i = e0 + tid; i < e1; i += 256) {
        unsigned p = binned[i];
        int t = (int)(p >> 16), s = (int)(p & 0xffffu);
        int lb = ((t - t0) << 1) | (s >= CHN);
        int pos = colbase + lrp[lb] + atomicAdd(&fillc[lb], 1);
        col[pos] = (unsigned short)s;
    }
    __syncthreads();
    for (int lb = tid; lb < BPB; lb += 256) {
        int c = cnt[lb];
        int pc = (c + 3) & ~3;
        int b2 = colbase + lrp[lb];
        for (int q = c; q < pc; ++q) col[b2 + q] = SENT;
    }
}

// ---------------------------------------------------------------------------
// degree-sort (two-level counting sort on iteration count, descending)
// ---------------------------------------------------------------------------
__device__ __forceinline__ int node_bin2(const int2* __restrict__ nspan, int i) {
    int iters = (nspan[i].y - nspan[i].x) >> 2;
    if (iters > NBINS - 1) iters = NBINS - 1;
    return (NBINS - 1) - iters;
}

__global__ __launch_bounds__(256) void k_hist2(const int2* __restrict__ nspan,
                                               int* __restrict__ bhistS,
                                               int* __restrict__ lrankS) {
    __shared__ int h[NBINS];
    const int tid = threadIdx.x;
    if (tid < NBINS) h[tid] = 0;
    __syncthreads();
    const int i = blockIdx.x * 256 + tid;
    if (i < N_NODES) lrankS[i] = atomicAdd(&h[node_bin2(nspan, i)], 1);
    __syncthreads();
    if (tid < NBINS) bhistS[tid * NBLKN + blockIdx.x] = h[tid];
}

__global__ __launch_bounds__(256) void k_colscan(int* __restrict__ bhistS,
                                                 int* __restrict__ bintotS) {
    const int b = blockIdx.x, tid = threadIdx.x;
    int v = (tid < NBLKN) ? bhistS[b * NBLKN + tid] : 0;
    __shared__ int sm[256];
    sm[tid] = v;
    __syncthreads();
    for (int off = 1; off < 256; off <<= 1) {
        int t = (tid >= off) ? sm[tid - off] : 0;
        __syncthreads();
        sm[tid] += t;
        __syncthreads();
    }
    if (tid < NBLKN) bhistS[b * NBLKN + tid] = sm[tid] - v;
    if (tid == 255) bintotS[b] = sm[255];
}

__global__ void k_binscan(const int* __restrict__ bintotS, int* __restrict__ binoffS) {
    int tid = threadIdx.x;
    int v = (tid < NBINS) ? bintotS[tid] : 0;
    int s = v;
#pragma unroll
    for (int off = 1; off < 64; off <<= 1) {
        int t = __shfl_up(s, off, 64);
        if (tid >= off) s += t;
    }
    if (tid < NBINS) binoffS[tid] = s - v;
}

__global__ __launch_bounds__(256) void k_sortscatter(const int2* __restrict__ nspan,
                                                     const int* __restrict__ binoffS,
                                                     const int* __restrict__ bhistS,
                                                     const int* __restrict__ lrankS,
                                                     int* __restrict__ perm,
                                                     int2* __restrict__ span) {
    int i = blockIdx.x * 256 + threadIdx.x;
    if (i >= N_NODES) return;
    int b = node_bin2(nspan, i);
    int pos = binoffS[b] + bhistS[b * NBLKN + blockIdx.x] + lrankS[i];
    perm[pos] = i;
    span[pos] = nspan[i];
}

// ---------------------------------------------------------------------------
// GEMM: writes bf16 output split into two feature planes (32 feats each):
// plane h holds features [h*32, h*32+32) for all nodes (3.2MB, L2-resident).
// ---------------------------------------------------------------------------
template <int K, bool AFFINE, bool HBF16>
__global__ __launch_bounds__(256) void k_gemm(const void* __restrict__ Hv,
                                              const float* __restrict__ W,
                                              const float* __restrict__ dinv,
                                              const float* __restrict__ affine,
                                              unsigned short* __restrict__ ts0,
                                              unsigned short* __restrict__ ts1) {
    __shared__ float Ws[K * HID];
    __shared__ float As[2 * K];
    const int tid = threadIdx.x;
    for (int i = tid * 4; i < K * HID; i += 256 * 4)
        *(float4*)&Ws[i] = *(const float4*)&W[i];
    if (AFFINE) {
        if (tid < (2 * K) / 4)
            *(float4*)&As[tid * 4] = *(const float4*)&affine[tid * 4];
    }
    __syncthreads();

    const int quad = tid & 3;
    const int rp_  = tid >> 2;
    const int row  = blockIdx.x * 128 + rp_ * 2;
    const int c0   = quad * 16;
    const bool v0  = row < N_NODES;
    const bool v1  = row + 1 < N_NODES;

    float acc0[16], acc1[16];
#pragma unroll
    for (int i = 0; i < 16; ++i) { acc0[i] = 0.f; acc1[i] = 0.f; }

    const float*          h0f = (const float*)Hv + (size_t)row * K;
    const unsigned short* h0b = (const unsigned short*)Hv + (size_t)row * K;
    const float4 z4 = make_float4(0.f, 0.f, 0.f, 0.f);

#pragma unroll 2
    for (int k = 0; k < K; k += 4) {
        float4 ha, hb;
        if constexpr (HBF16) {
            ushort4 ua = v0 ? *(const ushort4*)(h0b + k)     : make_ushort4(0, 0, 0, 0);
            ushort4 ub = v1 ? *(const ushort4*)(h0b + K + k) : make_ushort4(0, 0, 0, 0);
            ha = make_float4(b2f(ua.x), b2f(ua.y), b2f(ua.z), b2f(ua.w));
            hb = make_float4(b2f(ub.x), b2f(ub.y), b2f(ub.z), b2f(ub.w));
        } else {
            ha = v0 ? *(const float4*)(h0f + k)     : z4;
            hb = v1 ? *(const float4*)(h0f + K + k) : z4;
        }
        if (AFFINE) {
            const float4 sc = *(const float4*)&As[k];
            const float4 sh = *(const float4*)&As[K + k];
            ha.x = fmaxf(0.f, fmaf(ha.x, sc.x, sh.x));
            ha.y = fmaxf(0.f, fmaf(ha.y, sc.y, sh.y));
            ha.z = fmaxf(0.f, fmaf(ha.z, sc.z, sh.z));
            ha.w = fmaxf(0.f, fmaf(ha.w, sc.w, sh.w));
            hb.x = fmaxf(0.f, fmaf(hb.x, sc.x, sh.x));
            hb.y = fmaxf(0.f, fmaf(hb.y, sc.y, sh.y));
            hb.z = fmaxf(0.f, fmaf(hb.z, sc.z, sh.z));
            hb.w = fmaxf(0.f, fmaf(hb.w, sc.w, sh.w));
        }
        const float hA[4] = { ha.x, ha.y, ha.z, ha.w };
        const float hB[4] = { hb.x, hb.y, hb.z, hb.w };
#pragma unroll
        for (int j = 0; j < 4; ++j) {
            const float4* wr = (const float4*)&Ws[(k + j) * HID + c0];
            const float xa = hA[j], xb = hB[j];
#pragma unroll
            for (int q = 0; q < 4; ++q) {
                const float4 wv = wr[q];
                acc0[q * 4 + 0] = fmaf(xa, wv.x, acc0[q * 4 + 0]);
                acc0[q * 4 + 1] = fmaf(xa, wv.y, acc0[q * 4 + 1]);
                acc0[q * 4 + 2] = fmaf(xa, wv.z, acc0[q * 4 + 2]);
                acc0[q * 4 + 3] = fmaf(xa, wv.w, acc0[q * 4 + 3]);
                acc1[q * 4 + 0] = fmaf(xb, wv.x, acc1[q * 4 + 0]);
                acc1[q * 4 + 1] = fmaf(xb, wv.y, acc1[q * 4 + 1]);
                acc1[q * 4 + 2] = fmaf(xb, wv.z, acc1[q * 4 + 2]);
                acc1[q * 4 + 3] = fmaf(xb, wv.w, acc1[q * 4 + 3]);
            }
        }
    }

    unsigned short* plane = (c0 < 32) ? ts0 : ts1;
    const int pc0 = c0 & 31;
    if (v0) {
        const float d = dinv[row];
        uint4 p0, p1;
        p0.x = f2b2(acc0[0] * d,  acc0[1] * d);
        p0.y = f2b2(acc0[2] * d,  acc0[3] * d);
        p0.z = f2b2(acc0[4] * d,  acc0[5] * d);
        p0.w = f2b2(acc0[6] * d,  acc0[7] * d);
        p1.x = f2b2(acc0[8] * d,  acc0[9] * d);
        p1.y = f2b2(acc0[10] * d, acc0[11] * d);
        p1.z = f2b2(acc0[12] * d, acc0[13] * d);
        p1.w = f2b2(acc0[14] * d, acc0[15] * d);
        uint4* dst = (uint4*)&plane[(size_t)row * 32 + pc0];
        dst[0] = p0; dst[1] = p1;
    }
    if (v1) {
        const float d = dinv[row + 1];
        uint4 p0, p1;
        p0.x = f2b2(acc1[0] * d,  acc1[1] * d);
        p0.y = f2b2(acc1[2] * d,  acc1[3] * d);
        p0.z = f2b2(acc1[4] * d,  acc1[5] * d);
        p0.w = f2b2(acc1[6] * d,  acc1[7] * d);
        p1.x = f2b2(acc1[8] * d,  acc1[9] * d);
        p1.y = f2b2(acc1[10] * d, acc1[11] * d);
        p1.z = f2b2(acc1[12] * d, acc1[13] * d);
        p1.w = f2b2(acc1[14] * d, acc1[15] * d);
        uint4* dst = (uint4*)&plane[(size_t)(row + 1) * 32 + pc0];
        dst[0] = p0; dst[1] = p1;
    }
}

#define ACC4A(r)                                            \
    a0 += u2f_lo(r.x); a1 += u2f_hi(r.x);                   \
    a2 += u2f_lo(r.y); a3 += u2f_hi(r.y);
#define ACC4B(r)                                            \
    b0 += u2f_lo(r.x); b1 += u2f_hi(r.x);                   \
    b2 += u2f_lo(r.y); b3 += u2f_hi(r.y);

// interleaved dual-node half-row gather: 8 uint2 row-loads in flight.
#define GATHER_PAIR_H(sA, sB)                                                   \
    {                                                                           \
        int eA = sA.x, eB = sB.x;                                               \
        const int endA = sA.y, endB = sB.y;                                     \
        const int lenA = endA - eA, lenB = endB - eB;                           \
        const int iters = (lenA > lenB ? lenA : lenB) >> 2;                     \
        u16x4 cA = __builtin_nontemporal_load((eA < endA) ? (const u16x4*)&col[eA] : (const u16x4*)sent4); \
        u16x4 cB = __builtin_nontemporal_load((eB < endB) ? (const u16x4*)&col[eB] : (const u16x4*)sent4); \
        for (int it = 0; it < iters; ++it) {                                    \
            eA += 4; eB += 4;                                                   \
            const u16x4 nA = __builtin_nontemporal_load((eA < endA) ? (const u16x4*)&col[eA] : (const u16x4*)sent4); \
            const u16x4 nB = __builtin_nontemporal_load((eB < endB) ? (const u16x4*)&col[eB] : (const u16x4*)sent4); \
            const uint2 rA0 = tsh[(size_t)cA.x * 8 + sl];                       \
            const uint2 rA1 = tsh[(size_t)cA.y * 8 + sl];                       \
            const uint2 rA2 = tsh[(size_t)cA.z * 8 + sl];                       \
            const uint2 rA3 = tsh[(size_t)cA.w * 8 + sl];                       \
            const uint2 rB0 = tsh[(size_t)cB.x * 8 + sl];                       \
            const uint2 rB1 = tsh[(size_t)cB.y * 8 + sl];                       \
            const uint2 rB2 = tsh[(size_t)cB.z * 8 + sl];                       \
            const uint2 rB3 = tsh[(size_t)cB.w * 8 + sl];                       \
            ACC4A(rA0) ACC4A(rA1) ACC4A(rA2) ACC4A(rA3)                         \
            ACC4B(rB0) ACC4B(rB1) ACC4B(rB2) ACC4B(rB3)                         \
            cA = nA; cB = nB;                                                   \
        }                                                                       \
    }

// ---------------------------------------------------------------------------
// Half-plane gather + BN epilogue (HALF = 0: feats 0-31, 1: feats 32-63).
// Plane (3.2MB) is L2-resident; pairing + interleave as before.
// ---------------------------------------------------------------------------
template <int HALF>
__global__ __launch_bounds__(256) void k_gather_bn_h(const uint2* __restrict__ tsh,
                                                     const int* __restrict__ perm,
                                                     const int2* __restrict__ span,
                                                     const unsigned short* __restrict__ col,
                                                     const unsigned short* __restrict__ sent4,
                                                     const float* __restrict__ dinv,
                                                     const float* __restrict__ bias,
                                                     unsigned short* __restrict__ y,
                                                     float* __restrict__ stats) {
    const int tid  = threadIdx.x;
    const int w    = tid >> 6;
    const int lane = tid & 63;
    const int grp  = lane >> 3;          // 0..7
    const int sl   = lane & 7;           // 4 features: HALF*32 + sl*4 ..
    const float4 bv = ((const float4*)(bias + HALF * 32))[sl];
    float s0=0.f,s1=0.f,s2=0.f,s3=0.f;
    float q0=0.f,q1=0.f,q2=0.f,q3=0.f;

    for (int p = blockIdx.x * 32 + w * 8 + grp; p < NPAIR; p += gridDim.x * 32) {
        const int idxA = p;
        const int idxB = N_NODES - 1 - p;
        const int nodeA = perm[idxA];
        const int nodeB = perm[idxB];
        const int2 sA = span[idxA];
        const int2 sB = span[idxB];
        const uint2 selfA = tsh[(size_t)nodeA * 8 + sl];
        const uint2 selfB = tsh[(size_t)nodeB * 8 + sl];
        float a0 = u2f_lo(selfA.x), a1 = u2f_hi(selfA.x);
        float a2 = u2f_lo(selfA.y), a3 = u2f_hi(selfA.y);
        float b0 = u2f_lo(selfB.x), b1 = u2f_hi(selfB.x);
        float b2 = u2f_lo(selfB.y), b3 = u2f_hi(selfB.y);

        GATHER_PAIR_H(sA, sB)

        const float dA = dinv[nodeA];
        const float dB = dinv[nodeB];
        const float vA0 = fmaf(a0, dA, bv.x), vA1 = fmaf(a1, dA, bv.y);
        const float vA2 = fmaf(a2, dA, bv.z), vA3 = fmaf(a3, dA, bv.w);
        const float vB0 = fmaf(b0, dB, bv.x), vB1 = fmaf(b1, dB, bv.y);
        const float vB2 = fmaf(b2, dB, bv.z), vB3 = fmaf(b3, dB, bv.w);
        u32x2 yA, yB;
        yA.x = f2b2(vA0, vA1); yA.y = f2b2(vA2, vA3);
        yB.x = f2b2(vB0, vB1); yB.y = f2b2(vB2, vB3);
        __builtin_nontemporal_store(yA, (u32x2*)(y + (size_t)nodeA * HID + HALF * 32 + sl * 4));
        __builtin_nontemporal_store(yB, (u32x2*)(y + (size_t)nodeB * HID + HALF * 32 + sl * 4));
        s0 += vA0 + vB0; q0 += vA0 * vA0 + vB0 * vB0;
        s1 += vA1 + vB1; q1 += vA1 * vA1 + vB1 * vB1;
        s2 += vA2 + vB2; q2 += vA2 * vA2 + vB2 * vB2;
        s3 += vA3 + vB3; q3 += vA3 * vA3 + vB3 * vB3;
    }

#pragma unroll
    for (int off = 8; off <= 32; off <<= 1) {
        s0 += __shfl_xor(s0, off, 64); q0 += __shfl_xor(q0, off, 64);
        s1 += __shfl_xor(s1, off, 64); q1 += __shfl_xor(q1, off, 64);
        s2 += __shfl_xor(s2, off, 64); q2 += __shfl_xor(q2, off, 64);
        s3 += __shfl_xor(s3, off, 64); q3 += __shfl_xor(q3, off, 64);
    }
    __shared__ float smS[4][32];
    __shared__ float smQ[4][32];
    if (grp == 0) {
        *(float4*)&smS[w][4 * sl] = make_float4(s0, s1, s2, s3);
        *(float4*)&smQ[w][4 * sl] = make_float4(q0, q1, q2, q3);
    }
    __syncthreads();
    if (tid < 32) {
        float t1 = smS[0][tid] + smS[1][tid] + smS[2][tid] + smS[3][tid];
        float t2 = smQ[0][tid] + smQ[1][tid] + smQ[2][tid] + smQ[3][tid];
        atomicAdd(&stats[HALF * 32 + tid],      t1);
        atomicAdd(&stats[64 + HALF * 32 + tid], t2);
    }
}

__global__ void k_bn_final(const float* __restrict__ stats,
                           const float* __restrict__ g,
                           const float* __restrict__ be,
                           float* __restrict__ affine) {
    int c = threadIdx.x;
    if (c < HID) {
        float mu  = stats[c] * (1.0f / N_NODES);
        float var = stats[64 + c] * (1.0f / N_NODES) - mu * mu;
        var = fmaxf(var, 0.f);
        float sc = g[c] * rsqrtf(var + EPS_BN);
        affine[c]       = sc;
        affine[HID + c] = fmaf(-mu, sc, be[c]);
    }
}

// ---------------------------------------------------------------------------
// Half-plane gather + final fc partial dot. HALF=0 stores, HALF=1 adds.
// ---------------------------------------------------------------------------
template <int HALF>
__global__ __launch_bounds__(256) void k_gather_final_h(const uint2* __restrict__ tsh,
                                                        const int* __restrict__ perm,
                                                        const int2* __restrict__ span,
                                                        const unsigned short* __restrict__ col,
                                                        const unsigned short* __restrict__ sent4,
                                                        const float* __restrict__ dinv,
                                                        const float* __restrict__ bias2,
                                                        const float* __restrict__ fcW,
                                                        const float* __restrict__ fcb,
                                                        float* __restrict__ out) {
    const int tid  = threadIdx.x;
    const int w    = tid >> 6;
    const int lane = tid & 63;
    const int grp  = lane >> 3;
    const int sl   = lane & 7;
    const float4 bv = ((const float4*)(bias2 + HALF * 32))[sl];
    const float4 fw = ((const float4*)(fcW  + HALF * 32))[sl];
    const float  fb = fcb[0];

    for (int p = blockIdx.x * 32 + w * 8 + grp; p < NPAIR; p += gridDim.x * 32) {
        const int idxA = p;
        const int idxB = N_NODES - 1 - p;
        const int nodeA = perm[idxA];
        const int nodeB = perm[idxB];
        const int2 sA = span[idxA];
        const int2 sB = span[idxB];
        const uint2 selfA = tsh[(size_t)nodeA * 8 + sl];
        const uint2 selfB = tsh[(size_t)nodeB * 8 + sl];
        float a0 = u2f_lo(selfA.x), a1 = u2f_hi(selfA.x);
        float a2 = u2f_lo(selfA.y), a3 = u2f_hi(selfA.y);
        float b0 = u2f_lo(selfB.x), b1 = u2f_hi(selfB.x);
        float b2 = u2f_lo(selfB.y), b3 = u2f_hi(selfB.y);

        GATHER_PAIR_H(sA, sB)

        const float dA = dinv[nodeA];
        const float dB = dinv[nodeB];
        float vA = fmaxf(0.f, fmaf(a0, dA, bv.x)) * fw.x
                 + fmaxf(0.f, fmaf(a1, dA, bv.y)) * fw.y
                 + fmaxf(0.f, fmaf(a2, dA, bv.z)) * fw.z
                 + fmaxf(0.f, fmaf(a3, dA, bv.w)) * fw.w;
        float vB = fmaxf(0.f, fmaf(b0, dB, bv.x)) * fw.x
                 + fmaxf(0.f, fmaf(b1, dB, bv.y)) * fw.y
                 + fmaxf(0.f, fmaf(b2, dB, bv.z)) * fw.z
                 + fmaxf(0.f, fmaf(b3, dB, bv.w)) * fw.w;
#pragma unroll
        for (int off = 4; off >= 1; off >>= 1) {
            vA += __shfl_xor(vA, off, 64);
            vB += __shfl_xor(vB, off, 64);
        }
        if (sl == 0) {
            if (HALF == 0) {
                out[nodeA] = vA + fb;
                out[nodeB] = vB + fb;
            } else {
                out[nodeA] += vA;
                out[nodeB] += vB;
            }
        }
    }
}

// ---------------------------------------------------------------------------
extern "C" void kernel_launch(void* const* d_in, const int* in_sizes, int n_in,
                              void* d_out, int out_size, void* d_ws, size_t ws_size,
                              hipStream_t stream) {
    const float* x    = (const float*)d_in[0];
    const int*   ei   = (const int*)d_in[1];
    const float* W0   = (const float*)d_in[2];
    const float* b0   = (const float*)d_in[3];
    const float* W1   = (const float*)d_in[4];
    const float* b1   = (const float*)d_in[5];
    const float* W2   = (const float*)d_in[6];
    const float* b2   = (const float*)d_in[7];
    const float* g0   = (const float*)d_in[8];
    const float* be0  = (const float*)d_in[9];
    const float* g1   = (const float*)d_in[10];
    const float* be1  = (const float*)d_in[11];
    const float* fcW  = (const float*)d_in[12];
    const float* fcb  = (const float*)d_in[13];
    float* out        = (float*)d_out;

    char* ws = (char*)d_ws;
    size_t off = 0;
    auto alloc = [&](size_t bytes) -> void* {
        size_t o = off;
        off += (bytes + 255) & ~(size_t)255;
        return (void*)(ws + o);
    };
    unsigned short* ts0  = (unsigned short*)alloc((size_t)(N_NODES + 1) * 32 * 2);
    unsigned short* ts1  = (unsigned short*)alloc((size_t)(N_NODES + 1) * 32 * 2);
    unsigned short* bufY = (unsigned short*)alloc((size_t)N_NODES * HID * 2);
    unsigned short* col  = (unsigned short*)alloc((size_t)(N_EDGES + NCBIN * MAXPAD + 16) * 2);
    unsigned int* packed = (unsigned int*)alloc((size_t)N_EDGES * 4);
    unsigned int* binned = (unsigned int*)alloc((size_t)N_EDGES * 4);
    unsigned short* lrankE = (unsigned short*)alloc((size_t)N_EDGES * 2);
    int*   bhE     = (int*)  alloc((size_t)NCBIN * NB1 * 4);
    int*   bintotE = (int*)  alloc((size_t)NCBIN * 4);
    int*   binbase = (int*)  alloc((size_t)(NCBIN + 1) * 4);
    int2*  nspan   = (int2*) alloc((size_t)N_NODES * 8);
    float* dinv    = (float*)alloc((size_t)N_NODES * 4);
    int*   perm    = (int*)  alloc((size_t)N_NODES * 4);
    int2*  span    = (int2*) alloc((size_t)N_NODES * 8);
    int*   lrankS  = (int*)  alloc((size_t)N_NODES * 4);
    int*   bhistS  = (int*)  alloc((size_t)NBINS * NBLKN * 4);
    int*   bintotS = (int*)  alloc((size_t)NBINS * 4);
    int*   binoffS = (int*)  alloc((size_t)NBINS * 4);
    unsigned short* sent = (unsigned short*)alloc(16);
    float* stats0  = (float*)alloc(2 * HID * 4);
    float* stats1  = (float*)alloc(2 * HID * 4);
    float* affine0 = (float*)alloc(2 * HID * 4);
    float* affine1 = (float*)alloc(2 * HID * 4);

    const int gGemm = (N_NODES + 127) / 128;
    const int gGath = (NPAIR + 31) / 32;       // 782 blocks

    // CSR build (binned, XCD-local)
    k_zero<<<1, 256, 0, stream>>>(stats0, stats1, ts0, ts1, sent);
    k_p1<<<NB1, 256, 0, stream>>>(ei, packed, lrankE, bhE);
    k_p1scan<<<NCBIN, 512, 0, stream>>>(bhE, bintotE);
    k_binbase<<<1, 256, 0, stream>>>(bintotE, binbase);
    k_p3<<<NB1, 256, 0, stream>>>(packed, lrankE, bhE, binbase, binned);
    k_p4<<<NCBIN, 256, 0, stream>>>(binned, binbase, col, nspan, dinv);
    // degree sort
    k_hist2<<<NBLKN, 256, 0, stream>>>(nspan, bhistS, lrankS);
    k_colscan<<<NBINS, 256, 0, stream>>>(bhistS, bintotS);
    k_binscan<<<1, 64, 0, stream>>>(bintotS, binoffS);
    k_sortscatter<<<NBLKN, 256, 0, stream>>>(nspan, binoffS, bhistS, lrankS, perm, span);

    // ---- layer 0
    k_gemm<NFEAT, false, false><<<gGemm, 256, 0, stream>>>(x, W0, dinv, nullptr, ts0, ts1);
    k_gather_bn_h<0><<<gGath, 256, 0, stream>>>((const uint2*)ts0, perm, span, col, sent, dinv, b0, bufY, stats0);
    k_gather_bn_h<1><<<gGath, 256, 0, stream>>>((const uint2*)ts1, perm, span, col, sent, dinv, b0, bufY, stats0);
    k_bn_final<<<1, 64, 0, stream>>>(stats0, g0, be0, affine0);

    // ---- layer 1
    k_gemm<HID, true, true><<<gGemm, 256, 0, stream>>>(bufY, W1, dinv, affine0, ts0, ts1);
    k_gather_bn_h<0><<<gGath, 256, 0, stream>>>((const uint2*)ts0, perm, span, col, sent, dinv, b1, bufY, stats1);
    k_gather_bn_h<1><<<gGath, 256, 0, stream>>>((const uint2*)ts1, perm, span, col, sent, dinv, b1, bufY, stats1);
    k_bn_final<<<1, 64, 0, stream>>>(stats1, g1, be1, affine1);

    // ---- layer 2
    k_gemm<HID, true, true><<<gGemm, 256, 0, stream>>>(bufY, W2, dinv, affine1, ts0, ts1);
    k_gather_final_h<0><<<gGath, 256, 0, stream>>>((const uint2*)ts0, perm, span, col, sent, dinv, b2, fcW, fcb, out);
    k_gather_final_h<1><<<gGath, 256, 0, stream>>>((const uint2*)ts1, perm, span, col, sent, dinv, b2, fcW, fcb, out);
}

// Round 17
// 197.602 us; speedup vs baseline: 1.2338x; 1.2338x over previous
//
#include <hip/hip_runtime.h>

#define N_NODES 50000
#define N_EDGES 800000
#define NFEAT   128
#define HID     64
#define EPS_BN  1e-5f
#define NCHUNK  2
#define CHN     (N_NODES / NCHUNK)          // 25000: src chunk split
#define SENT    50000                       // sentinel src (zeroed ts row)

// ---- binned edge sort params
#define NPB     256                         // dst nodes per coarse bin (t>>8)
#define NCBIN   196                         // ceil(50000/256)
#define BPB     (NPB * NCHUNK)              // buckets per bin = 512
#define EPBLK   2048
#define NB1     ((N_EDGES + EPBLK - 1) / EPBLK)   // 391
#define MAXPAD  (3 * BPB + 4)               // per-bin col slack

// ---- degree sort params
#define NBINS   64
#define NBLKN   ((N_NODES + 255) / 256)     // 196
#define NHEX    (N_NODES / 16)              // 3125

typedef unsigned int u32x4 __attribute__((ext_vector_type(4)));

// bf16 helpers
__device__ __forceinline__ float u2f_lo(unsigned int u) {
    union { unsigned int i; float f; } c; c.i = u << 16; return c.f;
}
__device__ __forceinline__ float u2f_hi(unsigned int u) {
    union { unsigned int i; float f; } c; c.i = u & 0xffff0000u; return c.f;
}
__device__ __forceinline__ float b2f(unsigned short u) {
    union { unsigned int i; float f; } c; c.i = ((unsigned int)u) << 16; return c.f;
}
__device__ __forceinline__ unsigned int f2b2(float lo, float hi) {
    union { float f; unsigned int i; } a, b;
    a.f = lo; b.f = hi;
    unsigned int x = (a.i + 0x7fffu + ((a.i >> 16) & 1u)) >> 16;
    unsigned int y = (b.i + 0x7fffu + ((b.i >> 16) & 1u)) & 0xffff0000u;
    return x | y;
}

// ---------------------------------------------------------------------------
__global__ void k_zero(float* __restrict__ st0, float* __restrict__ st1,
                       unsigned short* __restrict__ ts,
                       unsigned short* __restrict__ sent) {
    int i = threadIdx.x;
    if (i < 2 * HID) { st0[i] = 0.f; st1[i] = 0.f; }
    if (i < 32) ((unsigned int*)(ts + (size_t)N_NODES * HID))[i] = 0u;  // zero row
    if (i < 4) sent[i] = SENT;
}

// ---------------------------------------------------------------------------
// binned edge sort
// ---------------------------------------------------------------------------
__global__ __launch_bounds__(256) void k_p1(const int* __restrict__ ei,
                                            unsigned int* __restrict__ packed,
                                            unsigned short* __restrict__ lrankE,
                                            int* __restrict__ bhE) {
    __shared__ int h[NCBIN];
    const int tid = threadIdx.x;
    for (int i = tid; i < NCBIN; i += 256) h[i] = 0;
    __syncthreads();
    const int base = blockIdx.x * EPBLK;
#pragma unroll
    for (int it = 0; it < EPBLK / 256; ++it) {
        int e = base + it * 256 + tid;
        if (e < N_EDGES) {
            unsigned s = (unsigned)ei[e];
            unsigned t = (unsigned)ei[N_EDGES + e];
            packed[e] = (t << 16) | s;
            lrankE[e] = (unsigned short)atomicAdd(&h[t >> 8], 1);
        }
    }
    __syncthreads();
    for (int i = tid; i < NCBIN; i += 256) bhE[i * NB1 + blockIdx.x] = h[i];
}

__global__ __launch_bounds__(512) void k_p1scan(int* __restrict__ bhE,
                                                int* __restrict__ bintotE) {
    const int b = blockIdx.x, tid = threadIdx.x;
    int v = (tid < NB1) ? bhE[b * NB1 + tid] : 0;
    __shared__ int sm[512];
    sm[tid] = v;
    __syncthreads();
    for (int off = 1; off < 512; off <<= 1) {
        int t = (tid >= off) ? sm[tid - off] : 0;
        __syncthreads();
        sm[tid] += t;
        __syncthreads();
    }
    if (tid < NB1) bhE[b * NB1 + tid] = sm[tid] - v;
    if (tid == 511) bintotE[b] = sm[511];
}

__global__ void k_binbase(const int* __restrict__ bintotE, int* __restrict__ binbase) {
    const int tid = threadIdx.x;
    int v = (tid < NCBIN) ? bintotE[tid] : 0;
    __shared__ int sm[256];
    sm[tid] = v;
    __syncthreads();
    for (int off = 1; off < 256; off <<= 1) {
        int t = (tid >= off) ? sm[tid - off] : 0;
        __syncthreads();
        sm[tid] += t;
        __syncthreads();
    }
    if (tid < NCBIN) binbase[tid] = sm[tid] - v;
    if (tid == NCBIN - 1) binbase[NCBIN] = sm[tid];
}

__global__ __launch_bounds__(256) void k_p3(const unsigned int* __restrict__ packed,
                                            const unsigned short* __restrict__ lrankE,
                                            const int* __restrict__ bhE,
                                            const int* __restrict__ binbase,
                                            unsigned int* __restrict__ binned) {
    const int base = blockIdx.x * EPBLK;
#pragma unroll
    for (int it = 0; it < EPBLK / 256; ++it) {
        int e = base + it * 256 + threadIdx.x;
        if (e < N_EDGES) {
            unsigned p = packed[e];
            int bin = (int)(p >> 24);
            int pos = binbase[bin] + bhE[bin * NB1 + blockIdx.x] + lrankE[e];
            binned[pos] = p;
        }
    }
}

__global__ __launch_bounds__(256) void k_p4(const unsigned int* __restrict__ binned,
                                            const int* __restrict__ binbase,
                                            unsigned short* __restrict__ col,
                                            int2* __restrict__ nspan,
                                            float* __restrict__ dinv) {
    __shared__ int cnt[BPB];
    __shared__ int lrp[BPB];
    __shared__ int fillc[BPB];
    __shared__ int scanTmp[256];
    const int bin = blockIdx.x, tid = threadIdx.x;
    const int e0 = binbase[bin], e1 = binbase[bin + 1];
    const int t0 = bin * NPB;
    for (int i = tid; i < BPB; i += 256) { cnt[i] = 0; fillc[i] = 0; }
    __syncthreads();
    for (int i = e0 + tid; i < e1; i += 256) {
        unsigned p = binned[i];
        int t = (int)(p >> 16), s = (int)(p & 0xffffu);
        int lb = ((t - t0) << 1) | (s >= CHN);
        atomicAdd(&cnt[lb], 1);
    }
    __syncthreads();
    const int p0 = (cnt[2 * tid] + 3) & ~3;
    const int p1 = (cnt[2 * tid + 1] + 3) & ~3;
    const int mysum = p0 + p1;
    scanTmp[tid] = mysum;
    __syncthreads();
    for (int off = 1; off < 256; off <<= 1) {
        int t = (tid >= off) ? scanTmp[tid - off] : 0;
        __syncthreads();
        scanTmp[tid] += t;
        __syncthreads();
    }
    const int pre = scanTmp[tid] - mysum;
    lrp[2 * tid]     = pre;
    lrp[2 * tid + 1] = pre + p0;
    const int colbase = ((e0 + 3) & ~3) + bin * MAXPAD;
    {
        const int node = t0 + tid;
        if (node < N_NODES) {
            int st = colbase + pre;
            nspan[node] = make_int2(st, st + p0 + p1);
            dinv[node] = rsqrtf((float)(cnt[2 * tid] + cnt[2 * tid + 1] + 1));
        }
    }
    __syncthreads();
    for (int i = e0 + tid; i < e1; i += 256) {
        unsigned p = binned[i];
        int t = (int)(p >> 16), s = (int)(p & 0xffffu);
        int lb = ((t - t0) << 1) | (s >= CHN);
        int pos = colbase + lrp[lb] + atomicAdd(&fillc[lb], 1);
        col[pos] = (unsigned short)s;
    }
    __syncthreads();
    for (int lb = tid; lb < BPB; lb += 256) {
        int c = cnt[lb];
        int pc = (c + 3) & ~3;
        int b2 = colbase + lrp[lb];
        for (int q = c; q < pc; ++q) col[b2 + q] = SENT;
    }
}

// ---------------------------------------------------------------------------
// degree-sort (two-level counting sort on iteration count, descending)
// ---------------------------------------------------------------------------
__device__ __forceinline__ int node_bin2(const int2* __restrict__ nspan, int i) {
    int iters = (nspan[i].y - nspan[i].x) >> 2;
    if (iters > NBINS - 1) iters = NBINS - 1;
    return (NBINS - 1) - iters;
}

__global__ __launch_bounds__(256) void k_hist2(const int2* __restrict__ nspan,
                                               int* __restrict__ bhistS,
                                               int* __restrict__ lrankS) {
    __shared__ int h[NBINS];
    const int tid = threadIdx.x;
    if (tid < NBINS) h[tid] = 0;
    __syncthreads();
    const int i = blockIdx.x * 256 + tid;
    if (i < N_NODES) lrankS[i] = atomicAdd(&h[node_bin2(nspan, i)], 1);
    __syncthreads();
    if (tid < NBINS) bhistS[tid * NBLKN + blockIdx.x] = h[tid];
}

__global__ __launch_bounds__(256) void k_colscan(int* __restrict__ bhistS,
                                                 int* __restrict__ bintotS) {
    const int b = blockIdx.x, tid = threadIdx.x;
    int v = (tid < NBLKN) ? bhistS[b * NBLKN + tid] : 0;
    __shared__ int sm[256];
    sm[tid] = v;
    __syncthreads();
    for (int off = 1; off < 256; off <<= 1) {
        int t = (tid >= off) ? sm[tid - off] : 0;
        __syncthreads();
        sm[tid] += t;
        __syncthreads();
    }
    if (tid < NBLKN) bhistS[b * NBLKN + tid] = sm[tid] - v;
    if (tid == 255) bintotS[b] = sm[255];
}

__global__ void k_binscan(const int* __restrict__ bintotS, int* __restrict__ binoffS) {
    int tid = threadIdx.x;
    int v = (tid < NBINS) ? bintotS[tid] : 0;
    int s = v;
#pragma unroll
    for (int off = 1; off < 64; off <<= 1) {
        int t = __shfl_up(s, off, 64);
        if (tid >= off) s += t;
    }
    if (tid < NBINS) binoffS[tid] = s - v;
}

__global__ __launch_bounds__(256) void k_sortscatter(const int2* __restrict__ nspan,
                                                     const int* __restrict__ binoffS,
                                                     const int* __restrict__ bhistS,
                                                     const int* __restrict__ lrankS,
                                                     int* __restrict__ perm,
                                                     int2* __restrict__ span) {
    int i = blockIdx.x * 256 + threadIdx.x;
    if (i >= N_NODES) return;
    int b = node_bin2(nspan, i);
    int pos = binoffS[b] + bhistS[b * NBLKN + blockIdx.x] + lrankS[i];
    perm[pos] = i;
    span[pos] = nspan[i];
}

// ---------------------------------------------------------------------------
// GEMM: ts[row][col] = bf16( dinv[row] * sum_k Hin[row][k] * W[k][col] )
// HBF16: H is bf16 (layers 1,2); else f32 (layer 0).
// ---------------------------------------------------------------------------
template <int K, bool AFFINE, bool HBF16>
__global__ __launch_bounds__(256) void k_gemm(const void* __restrict__ Hv,
                                              const float* __restrict__ W,
                                              const float* __restrict__ dinv,
                                              const float* __restrict__ affine,
                                              unsigned short* __restrict__ ts) {
    __shared__ float Ws[K * HID];
    __shared__ float As[2 * K];
    const int tid = threadIdx.x;
    for (int i = tid * 4; i < K * HID; i += 256 * 4)
        *(float4*)&Ws[i] = *(const float4*)&W[i];
    if (AFFINE) {
        if (tid < (2 * K) / 4)
            *(float4*)&As[tid * 4] = *(const float4*)&affine[tid * 4];
    }
    __syncthreads();

    const int quad = tid & 3;
    const int rp_  = tid >> 2;
    const int row  = blockIdx.x * 128 + rp_ * 2;
    const int c0   = quad * 16;
    const bool v0  = row < N_NODES;
    const bool v1  = row + 1 < N_NODES;

    float acc0[16], acc1[16];
#pragma unroll
    for (int i = 0; i < 16; ++i) { acc0[i] = 0.f; acc1[i] = 0.f; }

    const float*          h0f = (const float*)Hv + (size_t)row * K;
    const unsigned short* h0b = (const unsigned short*)Hv + (size_t)row * K;
    const float4 z4 = make_float4(0.f, 0.f, 0.f, 0.f);

#pragma unroll 2
    for (int k = 0; k < K; k += 4) {
        float4 ha, hb;
        if constexpr (HBF16) {
            ushort4 ua = v0 ? *(const ushort4*)(h0b + k)     : make_ushort4(0, 0, 0, 0);
            ushort4 ub = v1 ? *(const ushort4*)(h0b + K + k) : make_ushort4(0, 0, 0, 0);
            ha = make_float4(b2f(ua.x), b2f(ua.y), b2f(ua.z), b2f(ua.w));
            hb = make_float4(b2f(ub.x), b2f(ub.y), b2f(ub.z), b2f(ub.w));
        } else {
            ha = v0 ? *(const float4*)(h0f + k)     : z4;
            hb = v1 ? *(const float4*)(h0f + K + k) : z4;
        }
        if (AFFINE) {
            const float4 sc = *(const float4*)&As[k];
            const float4 sh = *(const float4*)&As[K + k];
            ha.x = fmaxf(0.f, fmaf(ha.x, sc.x, sh.x));
            ha.y = fmaxf(0.f, fmaf(ha.y, sc.y, sh.y));
            ha.z = fmaxf(0.f, fmaf(ha.z, sc.z, sh.z));
            ha.w = fmaxf(0.f, fmaf(ha.w, sc.w, sh.w));
            hb.x = fmaxf(0.f, fmaf(hb.x, sc.x, sh.x));
            hb.y = fmaxf(0.f, fmaf(hb.y, sc.y, sh.y));
            hb.z = fmaxf(0.f, fmaf(hb.z, sc.z, sh.z));
            hb.w = fmaxf(0.f, fmaf(hb.w, sc.w, sh.w));
        }
        const float hA[4] = { ha.x, ha.y, ha.z, ha.w };
        const float hB[4] = { hb.x, hb.y, hb.z, hb.w };
#pragma unroll
        for (int j = 0; j < 4; ++j) {
            const float4* wr = (const float4*)&Ws[(k + j) * HID + c0];
            const float xa = hA[j], xb = hB[j];
#pragma unroll
            for (int q = 0; q < 4; ++q) {
                const float4 wv = wr[q];
                acc0[q * 4 + 0] = fmaf(xa, wv.x, acc0[q * 4 + 0]);
                acc0[q * 4 + 1] = fmaf(xa, wv.y, acc0[q * 4 + 1]);
                acc0[q * 4 + 2] = fmaf(xa, wv.z, acc0[q * 4 + 2]);
                acc0[q * 4 + 3] = fmaf(xa, wv.w, acc0[q * 4 + 3]);
                acc1[q * 4 + 0] = fmaf(xb, wv.x, acc1[q * 4 + 0]);
                acc1[q * 4 + 1] = fmaf(xb, wv.y, acc1[q * 4 + 1]);
                acc1[q * 4 + 2] = fmaf(xb, wv.z, acc1[q * 4 + 2]);
                acc1[q * 4 + 3] = fmaf(xb, wv.w, acc1[q * 4 + 3]);
            }
        }
    }

    if (v0) {
        const float d = dinv[row];
        uint4 p0, p1;
        p0.x = f2b2(acc0[0] * d,  acc0[1] * d);
        p0.y = f2b2(acc0[2] * d,  acc0[3] * d);
        p0.z = f2b2(acc0[4] * d,  acc0[5] * d);
        p0.w = f2b2(acc0[6] * d,  acc0[7] * d);
        p1.x = f2b2(acc0[8] * d,  acc0[9] * d);
        p1.y = f2b2(acc0[10] * d, acc0[11] * d);
        p1.z = f2b2(acc0[12] * d, acc0[13] * d);
        p1.w = f2b2(acc0[14] * d, acc0[15] * d);
        uint4* dst = (uint4*)&ts[(size_t)row * HID + c0];
        dst[0] = p0; dst[1] = p1;
    }
    if (v1) {
        const float d = dinv[row + 1];
        uint4 p0, p1;
        p0.x = f2b2(acc1[0] * d,  acc1[1] * d);
        p0.y = f2b2(acc1[2] * d,  acc1[3] * d);
        p0.z = f2b2(acc1[4] * d,  acc1[5] * d);
        p0.w = f2b2(acc1[6] * d,  acc1[7] * d);
        p1.x = f2b2(acc1[8] * d,  acc1[9] * d);
        p1.y = f2b2(acc1[10] * d, acc1[11] * d);
        p1.z = f2b2(acc1[12] * d, acc1[13] * d);
        p1.w = f2b2(acc1[14] * d, acc1[15] * d);
        uint4* dst = (uint4*)&ts[(size_t)(row + 1) * HID + c0];
        dst[0] = p0; dst[1] = p1;
    }
}

#define ACC8A(r)                                            \
    a0 += u2f_lo(r.x); a1 += u2f_hi(r.x);                   \
    a2 += u2f_lo(r.y); a3 += u2f_hi(r.y);                   \
    a4 += u2f_lo(r.z); a5 += u2f_hi(r.z);                   \
    a6 += u2f_lo(r.w); a7 += u2f_hi(r.w);
#define ACC8B(r)                                            \
    b0 += u2f_lo(r.x); b1 += u2f_hi(r.x);                   \
    b2 += u2f_lo(r.y); b3 += u2f_hi(r.y);                   \
    b4 += u2f_lo(r.z); b5 += u2f_hi(r.z);                   \
    b6 += u2f_lo(r.w); b7 += u2f_hi(r.w);

// interleaved dual-node gather over ADJACENT sorted nodes (similar degree =>
// minimal sentinel waste); 8 row-gathers + 2 col quad loads in flight.
#define GATHER_PAIR(sA, sB)                                                     \
    {                                                                           \
        int eA = sA.x, eB = sB.x;                                               \
        const int endA = sA.y, endB = sB.y;                                     \
        const int lenA = endA - eA, lenB = endB - eB;                           \
        const int iters = (lenA > lenB ? lenA : lenB) >> 2;                     \
        ushort4 cA = *((eA < endA) ? (const ushort4*)&col[eA] : sent4);         \
        ushort4 cB = *((eB < endB) ? (const ushort4*)&col[eB] : sent4);         \
        for (int it = 0; it < iters; ++it) {                                    \
            eA += 4; eB += 4;                                                   \
            const ushort4 nA = *((eA < endA) ? (const ushort4*)&col[eA] : sent4); \
            const ushort4 nB = *((eB < endB) ? (const ushort4*)&col[eB] : sent4); \
            const uint4 rA0 = ts8[(size_t)cA.x * 8 + sl];                       \
            const uint4 rA1 = ts8[(size_t)cA.y * 8 + sl];                       \
            const uint4 rA2 = ts8[(size_t)cA.z * 8 + sl];                       \
            const uint4 rA3 = ts8[(size_t)cA.w * 8 + sl];                       \
            const uint4 rB0 = ts8[(size_t)cB.x * 8 + sl];                       \
            const uint4 rB1 = ts8[(size_t)cB.y * 8 + sl];                       \
            const uint4 rB2 = ts8[(size_t)cB.z * 8 + sl];                       \
            const uint4 rB3 = ts8[(size_t)cB.w * 8 + sl];                       \
            ACC8A(rA0) ACC8A(rA1) ACC8A(rA2) ACC8A(rA3)                         \
            ACC8B(rB0) ACC8B(rB1) ACC8B(rB2) ACC8B(rB3)                         \
            cA = nA; cB = nB;                                                   \
        }                                                                       \
    }

// ---------------------------------------------------------------------------
// Degree-sorted adjacent dual-node gather + BN epilogue (16 nodes/wave),
// bf16 y output.
// ---------------------------------------------------------------------------
__global__ __launch_bounds__(256) void k_gather_bn(const uint4* __restrict__ ts8,
                                                   const int* __restrict__ perm,
                                                   const int2* __restrict__ span,
                                                   const unsigned short* __restrict__ col,
                                                   const ushort4* __restrict__ sent4,
                                                   const float* __restrict__ dinv,
                                                   const float* __restrict__ bias,
                                                   unsigned short* __restrict__ y,
                                                   float* __restrict__ stats) {
    const int tid  = threadIdx.x;
    const int w    = tid >> 6;
    const int lane = tid & 63;
    const int grp  = lane >> 3;
    const int sl   = lane & 7;
    const float4 bv0 = ((const float4*)bias)[2 * sl];
    const float4 bv1 = ((const float4*)bias)[2 * sl + 1];
    float s0=0.f,s1=0.f,s2=0.f,s3=0.f,s4=0.f,s5=0.f,s6=0.f,s7=0.f;
    float q0=0.f,q1=0.f,q2=0.f,q3=0.f,q4=0.f,q5=0.f,q6=0.f,q7=0.f;

    for (int p = blockIdx.x * 4 + w; p < NHEX; p += gridDim.x * 4) {
        const int iA    = p * 16 + grp * 2;
        const int nodeA = perm[iA];
        const int nodeB = perm[iA + 1];
        const int2 sA   = span[iA];
        const int2 sB   = span[iA + 1];
        const uint4 selfA = ts8[(size_t)nodeA * 8 + sl];
        const uint4 selfB = ts8[(size_t)nodeB * 8 + sl];
        float a0 = u2f_lo(selfA.x), a1 = u2f_hi(selfA.x);
        float a2 = u2f_lo(selfA.y), a3 = u2f_hi(selfA.y);
        float a4 = u2f_lo(selfA.z), a5 = u2f_hi(selfA.z);
        float a6 = u2f_lo(selfA.w), a7 = u2f_hi(selfA.w);
        float b0 = u2f_lo(selfB.x), b1 = u2f_hi(selfB.x);
        float b2 = u2f_lo(selfB.y), b3 = u2f_hi(selfB.y);
        float b4 = u2f_lo(selfB.z), b5 = u2f_hi(selfB.z);
        float b6 = u2f_lo(selfB.w), b7 = u2f_hi(selfB.w);

        GATHER_PAIR(sA, sB)

        const float dA = dinv[nodeA];
        const float dB = dinv[nodeB];
        const float vA0 = fmaf(a0, dA, bv0.x), vA1 = fmaf(a1, dA, bv0.y);
        const float vA2 = fmaf(a2, dA, bv0.z), vA3 = fmaf(a3, dA, bv0.w);
        const float vA4 = fmaf(a4, dA, bv1.x), vA5 = fmaf(a5, dA, bv1.y);
        const float vA6 = fmaf(a6, dA, bv1.z), vA7 = fmaf(a7, dA, bv1.w);
        const float vB0 = fmaf(b0, dB, bv0.x), vB1 = fmaf(b1, dB, bv0.y);
        const float vB2 = fmaf(b2, dB, bv0.z), vB3 = fmaf(b3, dB, bv0.w);
        const float vB4 = fmaf(b4, dB, bv1.x), vB5 = fmaf(b5, dB, bv1.y);
        const float vB6 = fmaf(b6, dB, bv1.z), vB7 = fmaf(b7, dB, bv1.w);
        u32x4 yA, yB;
        yA.x = f2b2(vA0, vA1); yA.y = f2b2(vA2, vA3);
        yA.z = f2b2(vA4, vA5); yA.w = f2b2(vA6, vA7);
        yB.x = f2b2(vB0, vB1); yB.y = f2b2(vB2, vB3);
        yB.z = f2b2(vB4, vB5); yB.w = f2b2(vB6, vB7);
        *(u32x4*)(y + (size_t)nodeA * HID + sl * 8) = yA;
        *(u32x4*)(y + (size_t)nodeB * HID + sl * 8) = yB;
        s0 += vA0 + vB0; q0 += vA0 * vA0 + vB0 * vB0;
        s1 += vA1 + vB1; q1 += vA1 * vA1 + vB1 * vB1;
        s2 += vA2 + vB2; q2 += vA2 * vA2 + vB2 * vB2;
        s3 += vA3 + vB3; q3 += vA3 * vA3 + vB3 * vB3;
        s4 += vA4 + vB4; q4 += vA4 * vA4 + vB4 * vB4;
        s5 += vA5 + vB5; q5 += vA5 * vA5 + vB5 * vB5;
        s6 += vA6 + vB6; q6 += vA6 * vA6 + vB6 * vB6;
        s7 += vA7 + vB7; q7 += vA7 * vA7 + vB7 * vB7;
    }

#pragma unroll
    for (int off = 8; off <= 32; off <<= 1) {
        s0 += __shfl_xor(s0, off, 64); q0 += __shfl_xor(q0, off, 64);
        s1 += __shfl_xor(s1, off, 64); q1 += __shfl_xor(q1, off, 64);
        s2 += __shfl_xor(s2, off, 64); q2 += __shfl_xor(q2, off, 64);
        s3 += __shfl_xor(s3, off, 64); q3 += __shfl_xor(q3, off, 64);
        s4 += __shfl_xor(s4, off, 64); q4 += __shfl_xor(q4, off, 64);
        s5 += __shfl_xor(s5, off, 64); q5 += __shfl_xor(q5, off, 64);
        s6 += __shfl_xor(s6, off, 64); q6 += __shfl_xor(q6, off, 64);
        s7 += __shfl_xor(s7, off, 64); q7 += __shfl_xor(q7, off, 64);
    }
    __shared__ float smS[4][64];
    __shared__ float smQ[4][64];
    if (grp == 0) {
        *(float4*)&smS[w][8 * sl]     = make_float4(s0, s1, s2, s3);
        *(float4*)&smS[w][8 * sl + 4] = make_float4(s4, s5, s6, s7);
        *(float4*)&smQ[w][8 * sl]     = make_float4(q0, q1, q2, q3);
        *(float4*)&smQ[w][8 * sl + 4] = make_float4(q4, q5, q6, q7);
    }
    __syncthreads();
    if (tid < 64) {
        float t1 = smS[0][tid] + smS[1][tid] + smS[2][tid] + smS[3][tid];
        float t2 = smQ[0][tid] + smQ[1][tid] + smQ[2][tid] + smQ[3][tid];
        atomicAdd(&stats[tid],      t1);
        atomicAdd(&stats[64 + tid], t2);
    }
}

__global__ void k_bn_final(const float* __restrict__ stats,
                           const float* __restrict__ g,
                           const float* __restrict__ be,
                           float* __restrict__ affine) {
    int c = threadIdx.x;
    if (c < HID) {
        float mu  = stats[c] * (1.0f / N_NODES);
        float var = stats[64 + c] * (1.0f / N_NODES) - mu * mu;
        var = fmaxf(var, 0.f);
        float sc = g[c] * rsqrtf(var + EPS_BN);
        affine[c]       = sc;
        affine[HID + c] = fmaf(-mu, sc, be[c]);
    }
}

// ---------------------------------------------------------------------------
// Degree-sorted adjacent dual-node gather + final fc
// ---------------------------------------------------------------------------
__global__ __launch_bounds__(256) void k_gather_final(const uint4* __restrict__ ts8,
                                                      const int* __restrict__ perm,
                                                      const int2* __restrict__ span,
                                                      const unsigned short* __restrict__ col,
                                                      const ushort4* __restrict__ sent4,
                                                      const float* __restrict__ dinv,
                                                      const float* __restrict__ bias2,
                                                      const float* __restrict__ fcW,
                                                      const float* __restrict__ fcb,
                                                      float* __restrict__ out) {
    const int tid  = threadIdx.x;
    const int w    = tid >> 6;
    const int lane = tid & 63;
    const int grp  = lane >> 3;
    const int sl   = lane & 7;
    const float4 bv0 = ((const float4*)bias2)[2 * sl];
    const float4 bv1 = ((const float4*)bias2)[2 * sl + 1];
    const float4 fw0 = ((const float4*)fcW)[2 * sl];
    const float4 fw1 = ((const float4*)fcW)[2 * sl + 1];
    const float  fb  = fcb[0];

    for (int p = blockIdx.x * 4 + w; p < NHEX; p += gridDim.x * 4) {
        const int iA    = p * 16 + grp * 2;
        const int nodeA = perm[iA];
        const int nodeB = perm[iA + 1];
        const int2 sA   = span[iA];
        const int2 sB   = span[iA + 1];
        const uint4 selfA = ts8[(size_t)nodeA * 8 + sl];
        const uint4 selfB = ts8[(size_t)nodeB * 8 + sl];
        float a0 = u2f_lo(selfA.x), a1 = u2f_hi(selfA.x);
        float a2 = u2f_lo(selfA.y), a3 = u2f_hi(selfA.y);
        float a4 = u2f_lo(selfA.z), a5 = u2f_hi(selfA.z);
        float a6 = u2f_lo(selfA.w), a7 = u2f_hi(selfA.w);
        float b0 = u2f_lo(selfB.x), b1 = u2f_hi(selfB.x);
        float b2 = u2f_lo(selfB.y), b3 = u2f_hi(selfB.y);
        float b4 = u2f_lo(selfB.z), b5 = u2f_hi(selfB.z);
        float b6 = u2f_lo(selfB.w), b7 = u2f_hi(selfB.w);

        GATHER_PAIR(sA, sB)

        const float dA = dinv[nodeA];
        const float dB = dinv[nodeB];
        float vA = fmaxf(0.f, fmaf(a0, dA, bv0.x)) * fw0.x
                 + fmaxf(0.f, fmaf(a1, dA, bv0.y)) * fw0.y
                 + fmaxf(0.f, fmaf(a2, dA, bv0.z)) * fw0.z
                 + fmaxf(0.f, fmaf(a3, dA, bv0.w)) * fw0.w
                 + fmaxf(0.f, fmaf(a4, dA, bv1.x)) * fw1.x
                 + fmaxf(0.f, fmaf(a5, dA, bv1.y)) * fw1.y
                 + fmaxf(0.f, fmaf(a6, dA, bv1.z)) * fw1.z
                 + fmaxf(0.f, fmaf(a7, dA, bv1.w)) * fw1.w;
        float vB = fmaxf(0.f, fmaf(b0, dB, bv0.x)) * fw0.x
                 + fmaxf(0.f, fmaf(b1, dB, bv0.y)) * fw0.y
                 + fmaxf(0.f, fmaf(b2, dB, bv0.z)) * fw0.z
                 + fmaxf(0.f, fmaf(b3, dB, bv0.w)) * fw0.w
                 + fmaxf(0.f, fmaf(b4, dB, bv1.x)) * fw1.x
                 + fmaxf(0.f, fmaf(b5, dB, bv1.y)) * fw1.y
                 + fmaxf(0.f, fmaf(b6, dB, bv1.z)) * fw1.z
                 + fmaxf(0.f, fmaf(b7, dB, bv1.w)) * fw1.w;
#pragma unroll
        for (int off = 4; off >= 1; off >>= 1) {
            vA += __shfl_xor(vA, off, 64);
            vB += __shfl_xor(vB, off, 64);
        }
        if (sl == 0) {
            out[nodeA] = vA + fb;
            out[nodeB] = vB + fb;
        }
    }
}

// ---------------------------------------------------------------------------
extern "C" void kernel_launch(void* const* d_in, const int* in_sizes, int n_in,
                              void* d_out, int out_size, void* d_ws, size_t ws_size,
                              hipStream_t stream) {
    const float* x    = (const float*)d_in[0];
    const int*   ei   = (const int*)d_in[1];
    const float* W0   = (const float*)d_in[2];
    const float* b0   = (const float*)d_in[3];
    const float* W1   = (const float*)d_in[4];
    const float* b1   = (const float*)d_in[5];
    const float* W2   = (const float*)d_in[6];
    const float* b2   = (const float*)d_in[7];
    const float* g0   = (const float*)d_in[8];
    const float* be0  = (const float*)d_in[9];
    const float* g1   = (const float*)d_in[10];
    const float* be1  = (const float*)d_in[11];
    const float* fcW  = (const float*)d_in[12];
    const float* fcb  = (const float*)d_in[13];
    float* out        = (float*)d_out;

    char* ws = (char*)d_ws;
    size_t off = 0;
    auto alloc = [&](size_t bytes) -> void* {
        size_t o = off;
        off += (bytes + 255) & ~(size_t)255;
        return (void*)(ws + o);
    };
    unsigned short* ts   = (unsigned short*)alloc((size_t)(N_NODES + 1) * HID * 2);
    unsigned short* bufY = (unsigned short*)alloc((size_t)N_NODES * HID * 2);   // bf16 y
    unsigned short* col  = (unsigned short*)alloc((size_t)(N_EDGES + NCBIN * MAXPAD + 16) * 2);
    unsigned int* packed = (unsigned int*)alloc((size_t)N_EDGES * 4);
    unsigned int* binned = (unsigned int*)alloc((size_t)N_EDGES * 4);
    unsigned short* lrankE = (unsigned short*)alloc((size_t)N_EDGES * 2);
    int*   bhE     = (int*)  alloc((size_t)NCBIN * NB1 * 4);
    int*   bintotE = (int*)  alloc((size_t)NCBIN * 4);
    int*   binbase = (int*)  alloc((size_t)(NCBIN + 1) * 4);
    int2*  nspan   = (int2*) alloc((size_t)N_NODES * 8);
    float* dinv    = (float*)alloc((size_t)N_NODES * 4);
    int*   perm    = (int*)  alloc((size_t)N_NODES * 4);
    int2*  span    = (int2*) alloc((size_t)N_NODES * 8);
    int*   lrankS  = (int*)  alloc((size_t)N_NODES * 4);
    int*   bhistS  = (int*)  alloc((size_t)NBINS * NBLKN * 4);
    int*   bintotS = (int*)  alloc((size_t)NBINS * 4);
    int*   binoffS = (int*)  alloc((size_t)NBINS * 4);
    unsigned short* sent = (unsigned short*)alloc(16);
    float* stats0  = (float*)alloc(2 * HID * 4);
    float* stats1  = (float*)alloc(2 * HID * 4);
    float* affine0 = (float*)alloc(2 * HID * 4);
    float* affine1 = (float*)alloc(2 * HID * 4);

    const int gGemm = (N_NODES + 127) / 128;
    const int gGath = (NHEX + 3) / 4;          // 782 blocks

    // CSR build (binned, XCD-local)
    k_zero<<<1, 256, 0, stream>>>(stats0, stats1, ts, sent);
    k_p1<<<NB1, 256, 0, stream>>>(ei, packed, lrankE, bhE);
    k_p1scan<<<NCBIN, 512, 0, stream>>>(bhE, bintotE);
    k_binbase<<<1, 256, 0, stream>>>(bintotE, binbase);
    k_p3<<<NB1, 256, 0, stream>>>(packed, lrankE, bhE, binbase, binned);
    k_p4<<<NCBIN, 256, 0, stream>>>(binned, binbase, col, nspan, dinv);
    // degree sort
    k_hist2<<<NBLKN, 256, 0, stream>>>(nspan, bhistS, lrankS);
    k_colscan<<<NBINS, 256, 0, stream>>>(bhistS, bintotS);
    k_binscan<<<1, 64, 0, stream>>>(bintotS, binoffS);
    k_sortscatter<<<NBLKN, 256, 0, stream>>>(nspan, binoffS, bhistS, lrankS, perm, span);

    // ---- layer 0
    k_gemm<NFEAT, false, false><<<gGemm, 256, 0, stream>>>(x, W0, dinv, nullptr, ts);
    k_gather_bn<<<gGath, 256, 0, stream>>>((const uint4*)ts, perm, span, col, (const ushort4*)sent, dinv, b0, bufY, stats0);
    k_bn_final<<<1, 64, 0, stream>>>(stats0, g0, be0, affine0);

    // ---- layer 1
    k_gemm<HID, true, true><<<gGemm, 256, 0, stream>>>(bufY, W1, dinv, affine0, ts);
    k_gather_bn<<<gGath, 256, 0, stream>>>((const uint4*)ts, perm, span, col, (const ushort4*)sent, dinv, b1, bufY, stats1);
    k_bn_final<<<1, 64, 0, stream>>>(stats1, g1, be1, affine1);

    // ---- layer 2
    k_gemm<HID, true, true><<<gGemm, 256, 0, stream>>>(bufY, W2, dinv, affine1, ts);
    k_gather_final<<<gGath, 256, 0, stream>>>((const uint4*)ts, perm, span, col, (const ushort4*)sent, dinv, b2, fcW, fcb, out);
}